// Round 1
// baseline (242.139 us; speedup 1.0000x reference)
//
#include <hip/hip_runtime.h>
#include <cstdint>

typedef short short8 __attribute__((ext_vector_type(8)));
typedef float floatx4 __attribute__((ext_vector_type(4)));
typedef unsigned short ushortx4 __attribute__((ext_vector_type(4)));

__device__ __forceinline__ unsigned short f2bf(float f) {
  union { float f; unsigned u; } v; v.f = f;
  unsigned r = v.u + 0x7FFFu + ((v.u >> 16) & 1u);  // RNE
  return (unsigned short)(r >> 16);
}
__device__ __forceinline__ float bf2f(unsigned short h) {
  union { unsigned u; float f; } v; v.u = ((unsigned)h) << 16; return v.f;
}

#define MFMA16B(A, B, C) __builtin_amdgcn_mfma_f32_16x16x32_bf16((A), (B), (C), 0, 0, 0)

// Round fp32 weights to bf16 once per launch (d_ws is re-poisoned every call).
__global__ void __launch_bounds__(256) prep_weights(const float* __restrict__ wq,
                                                    const float* __restrict__ wp,
                                                    unsigned short* __restrict__ wq_h,
                                                    unsigned short* __restrict__ wp_h) {
  int i = blockIdx.x * 256 + threadIdx.x;
  if (i < 384 * 128) wq_h[i] = f2bf(wq[i]);
  if (i < 128 * 128) wp_h[i] = f2bf(wp[i]);
}

// One block = one window (b, g). 256 threads = 4 waves; wave w owns token rows 16w..16w+15.
__global__ void __launch_bounds__(256, 2) win_attn(const float* __restrict__ x,
                                                   const unsigned short* __restrict__ wqh,
                                                   const unsigned short* __restrict__ wph,
                                                   const float* __restrict__ bias,
                                                   float* __restrict__ out) {
  // pitches chosen so ds_read_b128 fragment reads are <=2-way bank conflicts
  __shared__ unsigned short Xh[64][136];  // x window, bf16 hi
  __shared__ unsigned short Xl[64][136];  // x window, bf16 lo (hi/lo 2-term QKV GEMM)
  __shared__ unsigned short Qs[64][40];   // per-head Q  [s][d]
  __shared__ unsigned short Ks[64][40];   // per-head K  [t][d]
  __shared__ unsigned short Vt[32][72];   // per-head V^T [d][t]
  __shared__ unsigned short Ps[64][72];   // per-head P  [s][t]
  __shared__ unsigned short Os[64][136];  // attention output [s][c]

  const int tid = threadIdx.x;
  const int bid = blockIdx.x;
  const int b = bid >> 6;
  const int g = bid & 63;
  const int gh = g >> 3, gw = g & 7;
  const size_t base = (size_t)b * 4096 * 128;

  // ---- stage x window -> LDS bf16 hi/lo ----
  {
    const int r = tid >> 2;            // window row 0..63
    const int c0 = (tid & 3) * 32;     // 32-float chunk
    const int n = gh * 512 + (r >> 3) * 64 + gw * 8 + (r & 7);
    const float4* xp = (const float4*)(x + base + (size_t)n * 128 + c0);
#pragma unroll
    for (int i = 0; i < 8; ++i) {
      float4 v = xp[i];
      ushortx4 hv, lv;
      hv[0] = f2bf(v.x); lv[0] = f2bf(v.x - bf2f(hv[0]));
      hv[1] = f2bf(v.y); lv[1] = f2bf(v.y - bf2f(hv[1]));
      hv[2] = f2bf(v.z); lv[2] = f2bf(v.z - bf2f(hv[2]));
      hv[3] = f2bf(v.w); lv[3] = f2bf(v.w - bf2f(hv[3]));
      *(ushortx4*)&Xh[r][c0 + i * 4] = hv;
      *(ushortx4*)&Xl[r][c0 + i * 4] = lv;
    }
  }
  __syncthreads();

  const int wv = tid >> 6;    // wave id = m-tile
  const int lane = tid & 63;
  const int lr = lane & 15;
  const int lg = lane >> 4;

  // A-fragments of X (rows 16wv+lr, all K=128): reused by every head
  short8 ah[4], al[4];
#pragma unroll
  for (int ks = 0; ks < 4; ++ks) {
    ah[ks] = *(const short8*)&Xh[16 * wv + lr][ks * 32 + lg * 8];
    al[ks] = *(const short8*)&Xl[16 * wv + lr][ks * 32 + lg * 8];
  }

  const float scale = 0.17677669529663687f;  // 32^-0.5

#pragma unroll 1
  for (int h = 0; h < 4; ++h) {
    // ---- QKV projection for head h: D[s][o] = X·Wqkv^T, 2-term hi/lo ----
#pragma unroll
    for (int m = 0; m < 3; ++m) {          // 0=q 1=k 2=v
#pragma unroll
      for (int j = 0; j < 2; ++j) {        // n-tile within hd=32
        floatx4 acc = {0.f, 0.f, 0.f, 0.f};
        const unsigned short* wb =
            wqh + (size_t)(m * 128 + h * 32 + j * 16 + lr) * 128 + lg * 8;
#pragma unroll
        for (int ks = 0; ks < 4; ++ks) {
          short8 bw = *(const short8*)(wb + ks * 32);  // B-frag: W[o][c], c-contiguous
          acc = MFMA16B(ah[ks], bw, acc);
          acc = MFMA16B(al[ks], bw, acc);
        }
#pragma unroll
        for (int r = 0; r < 4; ++r) {
          const int s = 16 * wv + 4 * lg + r;  // D row
          const int d = j * 16 + lr;           // D col (within head)
          const unsigned short hv = f2bf(acc[r]);
          if (m == 0)      Qs[s][d] = hv;
          else if (m == 1) Ks[s][d] = hv;
          else             Vt[d][s] = hv;      // store V transposed
        }
      }
    }
    __syncthreads();

    // ---- S^T = K·(Q as B): wave owns s-columns 16wv..16wv+15 ----
    floatx4 sc[4];
    {
      short8 bq = *(const short8*)&Qs[16 * wv + lr][lg * 8];
#pragma unroll
      for (int tt = 0; tt < 4; ++tt) {
        short8 ak = *(const short8*)&Ks[16 * tt + lr][lg * 8];
        floatx4 z = {0.f, 0.f, 0.f, 0.f};
        sc[tt] = MFMA16B(ak, bq, z);  // D[t][s] = sum_d K[t][d] Q[s][d]
      }
    }
    // softmax over t for column s = 16wv+lr; lane holds t = 16tt+4lg+r; 4-lane-group reduce
    float mx = -1e30f;
#pragma unroll
    for (int tt = 0; tt < 4; ++tt)
#pragma unroll
      for (int r = 0; r < 4; ++r) mx = fmaxf(mx, sc[tt][r]);
    mx = fmaxf(mx, __shfl_xor(mx, 16));
    mx = fmaxf(mx, __shfl_xor(mx, 32));
    float p[4][4];
    float sum = 0.f;
#pragma unroll
    for (int tt = 0; tt < 4; ++tt)
#pragma unroll
      for (int r = 0; r < 4; ++r) {
        float e = __expf(scale * (sc[tt][r] - mx));
        p[tt][r] = e;
        sum += e;
      }
    sum += __shfl_xor(sum, 16);
    sum += __shfl_xor(sum, 32);
    const float inv = 1.f / sum;
#pragma unroll
    for (int tt = 0; tt < 4; ++tt) {  // write P[s][t] (t-contiguous groups of 4)
      ushortx4 pv;
#pragma unroll
      for (int r = 0; r < 4; ++r) pv[r] = f2bf(p[tt][r] * inv);
      *(ushortx4*)&Ps[16 * wv + lr][16 * tt + 4 * lg] = pv;
    }
    __syncthreads();

    // ---- O^T = V^T·P^T : wave owns s-columns 16wv..16wv+15 ----
    floatx4 o0 = {0.f, 0.f, 0.f, 0.f}, o1 = {0.f, 0.f, 0.f, 0.f};
#pragma unroll
    for (int ks = 0; ks < 2; ++ks) {
      short8 bp  = *(const short8*)&Ps[16 * wv + lr][ks * 32 + lg * 8];
      short8 av0 = *(const short8*)&Vt[lr][ks * 32 + lg * 8];
      short8 av1 = *(const short8*)&Vt[16 + lr][ks * 32 + lg * 8];
      o0 = MFMA16B(av0, bp, o0);
      o1 = MFMA16B(av1, bp, o1);
    }
#pragma unroll
    for (int r = 0; r < 4; ++r) {
      const int s = 16 * wv + lr;                      // D col
      Os[s][h * 32 + 4 * lg + r]      = f2bf(o0[r]);   // D rows = d
      Os[s][h * 32 + 16 + 4 * lg + r] = f2bf(o1[r]);
    }
    __syncthreads();  // protects Qs/Ks/Vt/Ps reuse next head + O before proj
  }

  // ---- final projection: out[s][o] = O[s][c]·Wp[o][c] + bias[o] ----
  short8 ao[4];
#pragma unroll
  for (int ks = 0; ks < 4; ++ks)
    ao[ks] = *(const short8*)&Os[16 * wv + lr][ks * 32 + lg * 8];
#pragma unroll
  for (int nt = 0; nt < 8; ++nt) {
    floatx4 acc = {0.f, 0.f, 0.f, 0.f};
    const unsigned short* wb = wph + (size_t)(nt * 16 + lr) * 128 + lg * 8;
#pragma unroll
    for (int ks = 0; ks < 4; ++ks)
      acc = MFMA16B(ao[ks], *(const short8*)(wb + ks * 32), acc);
    const float bb = bias[nt * 16 + lr];
#pragma unroll
    for (int r = 0; r < 4; ++r) {
      const int s = 16 * wv + 4 * lg + r;
      const int n = gh * 512 + (s >> 3) * 64 + gw * 8 + (s & 7);
      out[base + (size_t)n * 128 + nt * 16 + lr] = acc[r] + bb;
    }
  }
}

extern "C" void kernel_launch(void* const* d_in, const int* in_sizes, int n_in,
                              void* d_out, int out_size, void* d_ws, size_t ws_size,
                              hipStream_t stream) {
  (void)in_sizes; (void)n_in; (void)out_size; (void)ws_size;
  const float* x  = (const float*)d_in[0];
  const float* wq = (const float*)d_in[1];
  const float* wp = (const float*)d_in[2];
  const float* bp = (const float*)d_in[3];
  float* out = (float*)d_out;
  unsigned short* wq_h = (unsigned short*)d_ws;          // 384*128 bf16
  unsigned short* wp_h = wq_h + 384 * 128;               // 128*128 bf16
  prep_weights<<<192, 256, 0, stream>>>(wq, wp, wq_h, wp_h);
  win_attn<<<2048, 256, 0, stream>>>(x, wq_h, wp_h, bp, out);
}